// Round 14
// baseline (145.782 us; speedup 1.0000x reference)
//
#include <hip/hip_runtime.h>
#include <hip/hip_bf16.h>

#define CC 128

typedef __attribute__((ext_vector_type(8))) short short8;
typedef __attribute__((ext_vector_type(16))) float f32x16;

union I4S8 { int4 i; short8 s; int2 h[2]; };

__device__ __forceinline__ unsigned short f2bfu(float f) {
  union { float f; unsigned int i; } x; x.f = f;
  unsigned int r = x.i + 0x7fffu + ((x.i >> 16) & 1u);
  return (unsigned short)(r >> 16);
}
__device__ __forceinline__ short f2bfs(float f) { return (short)f2bfu(f); }
// packed f32x2 -> bf16x2 via compiler intrinsic (RNE, emits v_cvt_pk_bf16_f32)
__device__ __forceinline__ unsigned int pk2(float a, float b) {
  union { __hip_bfloat162 h; unsigned int u; } c;
  c.h = __float22bfloat162_rn(make_float2(a, b));
  return c.u;
}
__device__ __forceinline__ float bflo(unsigned int u) {
  union { unsigned int i; float f; } x; x.i = u << 16; return x.f;
}
__device__ __forceinline__ float bfhi(unsigned int u) {
  union { unsigned int i; float f; } x; x.i = u & 0xffff0000u; return x.f;
}
// guaranteed single-instruction 2^x (v_exp_f32); 1-src/1-dst asm fallback
__device__ __forceinline__ float exp2_raw(float x) {
#if __has_builtin(__builtin_amdgcn_exp2f)
  return __builtin_amdgcn_exp2f(x);
#else
  float r; asm("v_exp_f32 %0, %1" : "=v"(r) : "v"(x)); return r;
#endif
}
__device__ __forceinline__ f32x16 fzero16() {
  f32x16 z;
#pragma unroll
  for (int i = 0; i < 16; ++i) z[i] = 0.f;
  return z;
}
__device__ __forceinline__ void ld8f(const float* p, float* f) {
  float4 a = *(const float4*)p, b = *(const float4*)(p + 4);
  f[0]=a.x; f[1]=a.y; f[2]=a.z; f[3]=a.w; f[4]=b.x; f[5]=b.y; f[6]=b.z; f[7]=b.w;
}

// 1/sqrt(16) * log2(e): folded into Q so attention works in log2 domain
#define QSC 0.3606737602f

// ---------------- W: fp32 -> bf16 weight conversion ----------------
__global__ __launch_bounds__(256) void k_cvtw(
    const float* __restrict__ wil, const float* __restrict__ wol,
    const float* __restrict__ wis, const float* __restrict__ wos,
    short* __restrict__ o) {
  const int idx = (blockIdx.x * 256 + threadIdx.x) * 8;
  const float* src; int off;
  if (idx < 49152)       { src = wil; off = idx; }
  else if (idx < 65536)  { src = wol; off = idx - 49152; }
  else if (idx < 114688) { src = wis; off = idx - 65536; }
  else                   { src = wos; off = idx - 114688; }
  float f[8];
  ld8f(src + off, f);
  short8 r;
#pragma unroll
  for (int j = 0; j < 8; ++j) r[j] = f2bfs(f[j]);
  *(short8*)(o + idx) = r;
}

// ---------------- K1: long QKV projection, MFMA ----------------
// Emits bf16 Q/K/V [pair=b*8+hh][l][d] and pos_ct[c][tok] bf16.
// Stager: thread = (c-pair, 8-token segment); X writes are b32 pairs.
__global__ __launch_bounds__(256) void k_proj_long(
    const float* __restrict__ q, const float* __restrict__ k,
    const float* __restrict__ v, const float* __restrict__ pq,
    const float* __restrict__ pk,
    const short* __restrict__ wbf, const float* __restrict__ b_in,
    short* __restrict__ qb, short* __restrict__ kb, short* __restrict__ vb,
    short* __restrict__ pos_ct) {
  __shared__ short XQ[32][132], XK[32][132], XV[32][132];
  const int tid = threadIdx.x;
  const int wid = tid >> 6, lane = tid & 63;
  const int l31 = lane & 31, g = lane >> 5;
  const int tok0 = blockIdx.x * 32;
  const int l = tok0 >> 9, b0 = tok0 & 511;
  const int t = l >> 4, bh = (l >> 2) & 3, bw = l & 3;
  const int nb = b0 >> 8, ph0 = (b0 >> 4) & 15;
  {
    const int p = tid & 63;          // c-pair: channels 2p, 2p+1
    const int seg = tid >> 6;        // 0..3 -> tokens seg*8..seg*8+7
    const int h = bh * 16 + ph0 + (seg >> 1);
    const int w0 = bw * 16 + (seg & 1) * 8;
    const int j0 = seg * 8;
    float aq[2][8], ak[2][8], av[2][8], pp0[2][8];
#pragma unroll
    for (int cc = 0; cc < 2; ++cc) {
      const int c = 2 * p + cc;
      const size_t gb = (((size_t)(nb * CC + c) * 4 + t) << 12) + h * 64 + w0;
      float a[8], pp[8];
      ld8f(q + gb, a); ld8f(pq + gb, pp);
#pragma unroll
      for (int j = 0; j < 8; ++j) { aq[cc][j] = a[j] + pp[j]; pp0[cc][j] = pp[j]; }
      ld8f(k + gb, a); ld8f(pk + gb, pp);
#pragma unroll
      for (int j = 0; j < 8; ++j) ak[cc][j] = a[j] + pp[j];
      ld8f(v + gb, av[cc]);
    }
#pragma unroll
    for (int cc = 0; cc < 2; ++cc) {
      short8 s;
#pragma unroll
      for (int j = 0; j < 8; ++j) s[j] = f2bfs(pp0[cc][j]);
      *(short8*)(pos_ct + (size_t)(2 * p + cc) * 32768 + tok0 + j0) = s;
    }
#pragma unroll
    for (int j = 0; j < 8; ++j) {
      *(int*)&XQ[j0 + j][2 * p] = (int)pk2(aq[0][j], aq[1][j]);
      *(int*)&XK[j0 + j][2 * p] = (int)pk2(ak[0][j], ak[1][j]);
      *(int*)&XV[j0 + j][2 * p] = (int)pk2(av[0][j], av[1][j]);
    }
  }
  __syncthreads();
  for (int i = 0; i < 3; ++i) {
    const int nt = wid + 4 * i;
    const int nch = nt * 32 + l31;
    const int which = nt >> 2;
    const short (*X)[132] = (which == 0) ? XQ : (which == 1) ? XK : XV;
    f32x16 acc = fzero16();
#pragma unroll
    for (int k0 = 0; k0 < 128; k0 += 16) {
      I4S8 af;
      af.h[0] = *(const int2*)&X[l31][k0 + 8 * g];
      af.h[1] = *(const int2*)&X[l31][k0 + 8 * g + 4];
      short8 bf = *(const short8*)(wbf + nch * CC + k0 + 8 * g);
      acc = __builtin_amdgcn_mfma_f32_32x32x16_bf16(af.s, bf, acc, 0, 0, 0);
    }
    const float bias = b_in[nch];
    const int hh = (nch >> 4) & 7, d = nch & 15;
    short* dst = (which == 0) ? qb : (which == 1) ? kb : vb;
    const float sc = (which == 0) ? QSC : 1.0f;
#pragma unroll
    for (int r = 0; r < 16; ++r) {
      const int tt = (r & 3) + 8 * (r >> 2) + 4 * g;
      dst[((size_t)((b0 + tt) * 8 + hh) * 64 + l) * 16 + d] =
          f2bfs((acc[r] + bias) * sc);
    }
  }
}

// ---------------- K2: unified MFMA flash attention ----------------
// Q64/wave, optional split-K (static-max exp2 makes partials additive).
// Per-wave DOUBLE-BUFFERED V^T LDS tile [17][36] (ones row 16 -> acc[8]=lsum):
// stage tile t+1 while computing t, breaking the in-tile ds_write->ds_read stall.
template<int SEQ, int BATCH, int SPLITK>
__global__ __launch_bounds__(256) void k_attn(
    const short* __restrict__ qsp, const short* __restrict__ ksp,
    const short* __restrict__ vsp, short* __restrict__ ao) {
  __shared__ short vt[4][2][17 * 36];
  __shared__ float comb[2][64][19];   // used only when SPLITK==2
  const int tid = threadIdx.x;
  const int wid = tid >> 6, lane = tid & 63;
  const int l31 = lane & 31, g = lane >> 5;
  constexpr int QG = SEQ / 64;
  constexpr int NBLK = (BATCH * 8 * QG * SPLITK) / 4;
  // XCD-chunk swizzle (bijective: NBLK % 8 == 0)
  const int blk = (blockIdx.x & 7) * (NBLK / 8) + (blockIdx.x >> 3);
  const int gw = blk * 4 + wid;
  const int kh = (SPLITK == 2) ? (gw & 1) : 0;
  const int rest = (SPLITK == 2) ? (gw >> 1) : gw;
  const int pair = rest / QG;
  const int q0 = (rest % QG) * 64;
  const int batch = pair >> 3, hh = pair & 7;
  const size_t pbase = (size_t)pair * (SEQ * 16);
  short* vtw0 = &vt[wid][0][0];
  short* vtw1 = &vt[wid][1][0];
  if (lane < 18) {   // ones rows (A rows 16..31), both buffers, once
    *(int*)(vtw0 + 16 * 36 + 2 * lane) = 0x3F803F80;
    *(int*)(vtw1 + 16 * 36 + 2 * lane) = 0x3F803F80;
  }

  const short8 qf0 = *(const short8*)(qsp + pbase + (size_t)(q0 + l31) * 16 + 8 * g);
  const short8 qf1 = *(const short8*)(qsp + pbase + (size_t)(q0 + 32 + l31) * 16 + 8 * g);

  f32x16 acc0 = fzero16(), acc1 = fzero16();
  const int arow = (l31 < 16) ? l31 : 16;
  const short* vtr0 = vtw0 + arow * 36;
  const short* vtr1 = vtw1 + arow * 36;
  constexpr int NT = SEQ / 32 / SPLITK;   // key tiles per wave
  const int t0 = kh * NT;

  // stage key-tile kt into buffer buf
  auto stage = [&](int kt, short* buf) {
    const short8 vf =
        *(const short8*)(vsp + pbase + (size_t)(kt * 32 + l31) * 16 + 8 * g);
#pragma unroll
    for (int j = 0; j < 8; ++j) buf[(8 * g + j) * 36 + l31] = vf[j];
  };
  stage(t0, vtw0);

  for (int tt = 0; tt < NT; ++tt) {
    const short8 kf =
        *(const short8*)(ksp + pbase + (size_t)((t0 + tt) * 32 + l31) * 16 + 8 * g);
    if (tt + 1 < NT) stage(t0 + tt + 1, ((tt + 1) & 1) ? vtw1 : vtw0);

    f32x16 s0 = __builtin_amdgcn_mfma_f32_32x32x16_bf16(kf, qf0, fzero16(), 0, 0, 0);
    f32x16 s1 = __builtin_amdgcn_mfma_f32_32x32x16_bf16(kf, qf1, fzero16(), 0, 0, 0);

    I4S8 pa0, pb0, pa1, pb1;
#pragma unroll
    for (int j = 0; j < 4; ++j) {
      pa0.i[j] = (int)pk2(exp2_raw(s0[2 * j]), exp2_raw(s0[2 * j + 1]));
      pb0.i[j] = (int)pk2(exp2_raw(s0[8 + 2 * j]), exp2_raw(s0[9 + 2 * j]));
    }
#pragma unroll
    for (int j = 0; j < 4; ++j) {
      pa1.i[j] = (int)pk2(exp2_raw(s1[2 * j]), exp2_raw(s1[2 * j + 1]));
      pb1.i[j] = (int)pk2(exp2_raw(s1[8 + 2 * j]), exp2_raw(s1[9 + 2 * j]));
    }

    const short* vtr = (tt & 1) ? vtr1 : vtr0;
    I4S8 a1, a2;
    a1.h[0] = *(const int2*)(vtr + 4 * g);
    a1.h[1] = *(const int2*)(vtr + 8 + 4 * g);
    a2.h[0] = *(const int2*)(vtr + 16 + 4 * g);
    a2.h[1] = *(const int2*)(vtr + 24 + 4 * g);
    acc0 = __builtin_amdgcn_mfma_f32_32x32x16_bf16(a1.s, pa0.s, acc0, 0, 0, 0);
    acc0 = __builtin_amdgcn_mfma_f32_32x32x16_bf16(a2.s, pb0.s, acc0, 0, 0, 0);
    acc1 = __builtin_amdgcn_mfma_f32_32x32x16_bf16(a1.s, pa1.s, acc1, 0, 0, 0);
    acc1 = __builtin_amdgcn_mfma_f32_32x32x16_bf16(a2.s, pb1.s, acc1, 0, 0, 0);
  }

  if (SPLITK == 2) {
    // split-K combine: kh=1 deposits 18 partials/lane; kh=0 adds
    const int pi = wid >> 1;
    if (kh == 1) {
#pragma unroll
      for (int r = 0; r < 9; ++r) {
        comb[pi][lane][r] = acc0[r];
        comb[pi][lane][9 + r] = acc1[r];
      }
    }
    __syncthreads();
    if (kh == 1) return;
#pragma unroll
    for (int r = 0; r < 9; ++r) {
      acc0[r] += comb[pi][lane][r];
      acc1[r] += comb[pi][lane][9 + r];
    }
  }

  const float inv0 = 1.0f / acc0[8];   // ones-row accumulation = full lsum
  const float inv1 = 1.0f / acc1[8];
  const int qi = q0 + l31;
  short* dst0 = ao + ((size_t)qi * BATCH + batch) * CC + hh * 16 + 4 * g;
  short* dst1 = ao + ((size_t)(qi + 32) * BATCH + batch) * CC + hh * 16 + 4 * g;
  uint2 o1, o2;
  o1.x = pk2(acc0[0] * inv0, acc0[1] * inv0);
  o1.y = pk2(acc0[2] * inv0, acc0[3] * inv0);
  o2.x = pk2(acc0[4] * inv0, acc0[5] * inv0);
  o2.y = pk2(acc0[6] * inv0, acc0[7] * inv0);
  *(uint2*)dst0 = o1;
  *(uint2*)(dst0 + 8) = o2;
  o1.x = pk2(acc1[0] * inv1, acc1[1] * inv1);
  o1.y = pk2(acc1[2] * inv1, acc1[3] * inv1);
  o2.x = pk2(acc1[4] * inv1, acc1[5] * inv1);
  o2.y = pk2(acc1[6] * inv1, acc1[7] * inv1);
  *(uint2*)dst1 = o1;
  *(uint2*)(dst1 + 8) = o2;
}

// ---------------- K3: long out-proj + pos + short QKV proj (MFMA x2) ----------------
__global__ __launch_bounds__(256) void k_mid(
    const short* __restrict__ ao, const short* __restrict__ pos_ct,
    const short* __restrict__ wobf, const float* __restrict__ b_out_l,
    const short* __restrict__ wibf, const float* __restrict__ b_in_s,
    short* __restrict__ qb, short* __restrict__ kb, short* __restrict__ vb) {
  __shared__ short YQK[32][132], YV[32][132];
  const int tid = threadIdx.x;
  const int wid = tid >> 6, lane = tid & 63;
  const int l31 = lane & 31, g = lane >> 5;
  const int tok0 = blockIdx.x * 32;
  const int l = tok0 >> 9, b0 = tok0 & 511;
  const int t = l >> 4, bh = (l >> 2) & 3, bw = l & 3;
  const int nb = b0 >> 8, ph0 = (b0 >> 4) & 15;
  {
    const int nch = wid * 32 + l31;
    f32x16 acc = fzero16();
#pragma unroll
    for (int k0 = 0; k0 < 128; k0 += 16) {
      short8 af = *(const short8*)(ao + (size_t)(tok0 + l31) * CC + k0 + 8 * g);
      short8 bf = *(const short8*)(wobf + nch * CC + k0 + 8 * g);
      acc = __builtin_amdgcn_mfma_f32_32x32x16_bf16(af, bf, acc, 0, 0, 0);
    }
    const float bias = b_out_l[nch];
    float pos[16];
#pragma unroll
    for (int rr = 0; rr < 4; ++rr) {
      int2 pp = *(const int2*)(pos_ct + (size_t)nch * 32768 + tok0 + rr * 8 + 4 * g);
      pos[rr * 4 + 0] = bflo((unsigned int)pp.x);
      pos[rr * 4 + 1] = bfhi((unsigned int)pp.x);
      pos[rr * 4 + 2] = bflo((unsigned int)pp.y);
      pos[rr * 4 + 3] = bfhi((unsigned int)pp.y);
    }
#pragma unroll
    for (int r = 0; r < 16; ++r) {
      const int tt = (r & 3) + 8 * (r >> 2) + 4 * g;
      const float y = acc[r] + bias;
      YV[tt][nch] = f2bfs(y);
      YQK[tt][nch] = f2bfs(y + pos[r]);
    }
  }
  __syncthreads();
  const int bs = nb * 16 + bh * 4 + bw;
  const int ls0 = (t * 16 + ph0) * 16;
  for (int i = 0; i < 3; ++i) {
    const int nt = wid + 4 * i;
    const int nch = nt * 32 + l31;
    const int which = nt >> 2;
    const short (*X)[132] = (which == 2) ? YV : YQK;
    f32x16 acc = fzero16();
#pragma unroll
    for (int k0 = 0; k0 < 128; k0 += 16) {
      I4S8 af;
      af.h[0] = *(const int2*)&X[l31][k0 + 8 * g];
      af.h[1] = *(const int2*)&X[l31][k0 + 8 * g + 4];
      short8 bf = *(const short8*)(wibf + nch * CC + k0 + 8 * g);
      acc = __builtin_amdgcn_mfma_f32_32x32x16_bf16(af.s, bf, acc, 0, 0, 0);
    }
    const float bias = b_in_s[nch];
    const int hh = (nch >> 4) & 7, d = nch & 15;
    short* dst = (which == 0) ? qb : (which == 1) ? kb : vb;
    const float sc = (which == 0) ? QSC : 1.0f;
    const size_t base = ((size_t)(bs * 8 + hh) * 1024 + ls0) * 16 + d;
#pragma unroll
    for (int r = 0; r < 16; ++r) {
      const int tt = (r & 3) + 8 * (r >> 2) + 4 * g;
      dst[base + (size_t)tt * 16] = f2bfs((acc[r] + bias) * sc);
    }
  }
}

// ---------------- K4: short out-proj + scatter to (N,C,T,H,W) fp32, MFMA ----------------
__global__ __launch_bounds__(256) void k_out_short(
    const short* __restrict__ ao, const short* __restrict__ wbf,
    const float* __restrict__ b_out, float* __restrict__ out) {
  const int tid = threadIdx.x;
  const int wid = tid >> 6, lane = tid & 63;
  const int l31 = lane & 31, g = lane >> 5;
  const int bs = blockIdx.x & 31;
  const int qi0 = (blockIdx.x >> 5) << 5;
  const int nb = bs >> 4, bh = (bs >> 2) & 3, bw = bs & 3;
  const int t = qi0 >> 8, ph0 = (qi0 >> 4) & 15;
  const int nch = wid * 32 + l31;
  f32x16 acc = fzero16();
#pragma unroll
  for (int k0 = 0; k0 < 128; k0 += 16) {
    short8 af = *(const short8*)(ao + ((size_t)(qi0 + l31) * 32 + bs) * CC + k0 + 8 * g);
    short8 bf = *(const short8*)(wbf + nch * CC + k0 + 8 * g);
    acc = __builtin_amdgcn_mfma_f32_32x32x16_bf16(af, bf, acc, 0, 0, 0);
  }
  const float bias = b_out[nch];
#pragma unroll
  for (int rr = 0; rr < 4; ++rr) {
    const int tt0 = rr * 8 + 4 * g;
    const int ph_off = tt0 >> 4, pw = tt0 & 15;
    const int h = bh * 16 + ph0 + ph_off, w = bw * 16 + pw;
    const size_t adr = (((size_t)(nb * CC + nch) * 4 + t) << 12) + h * 64 + w;
    float4 f;
    f.x = acc[rr * 4 + 0] + bias; f.y = acc[rr * 4 + 1] + bias;
    f.z = acc[rr * 4 + 2] + bias; f.w = acc[rr * 4 + 3] + bias;
    *(float4*)(out + adr) = f;
  }
}

extern "C" void kernel_launch(void* const* d_in, const int* in_sizes, int n_in,
                              void* d_out, int out_size, void* d_ws, size_t ws_size,
                              hipStream_t stream) {
  (void)in_sizes; (void)n_in; (void)out_size; (void)ws_size;
  const float* q   = (const float*)d_in[0];
  const float* k   = (const float*)d_in[1];
  const float* v   = (const float*)d_in[2];
  const float* pq  = (const float*)d_in[3];
  const float* pk  = (const float*)d_in[4];
  const float* wil = (const float*)d_in[5];
  const float* bil = (const float*)d_in[6];
  const float* wol = (const float*)d_in[7];
  const float* bol = (const float*)d_in[8];
  const float* wis = (const float*)d_in[9];
  const float* bis = (const float*)d_in[10];
  const float* wos = (const float*)d_in[11];
  const float* bos = (const float*)d_in[12];

  short* qs     = (short*)d_ws;            // 4.19M shorts each region
  short* ksb    = qs + 4194304;
  short* vsb    = ksb + 4194304;
  short* ao     = vsb + 4194304;
  short* pos_ct = ao + 4194304;
  short* wbf    = pos_ct + 4194304;        // 131072 shorts

  k_cvtw<<<dim3(64), dim3(256), 0, stream>>>(wil, wol, wis, wos, wbf);
  k_proj_long<<<dim3(1024), dim3(256), 0, stream>>>(q, k, v, pq, pk, wbf, bil,
                                                    qs, ksb, vsb, pos_ct);
  k_attn<64, 512, 1><<<dim3(1024), dim3(256), 0, stream>>>(qs, ksb, vsb, ao);
  k_mid<<<dim3(1024), dim3(256), 0, stream>>>(ao, pos_ct, wbf + 49152, bol,
                                              wbf + 65536, bis, qs, ksb, vsb);
  k_attn<1024, 32, 2><<<dim3(2048), dim3(256), 0, stream>>>(qs, ksb, vsb, ao);
  k_out_short<<<dim3(1024), dim3(256), 0, stream>>>(ao, wbf + 114688, bos,
                                                    (float*)d_out);
}

// Round 15
// 141.069 us; speedup vs baseline: 1.0334x; 1.0334x over previous
//
#include <hip/hip_runtime.h>
#include <hip/hip_bf16.h>

#define CC 128

typedef __attribute__((ext_vector_type(8))) short short8;
typedef __attribute__((ext_vector_type(16))) float f32x16;

union I4S8 { int4 i; short8 s; int2 h[2]; };

__device__ __forceinline__ unsigned short f2bfu(float f) {
  union { float f; unsigned int i; } x; x.f = f;
  unsigned int r = x.i + 0x7fffu + ((x.i >> 16) & 1u);
  return (unsigned short)(r >> 16);
}
__device__ __forceinline__ short f2bfs(float f) { return (short)f2bfu(f); }
// packed f32x2 -> bf16x2 via compiler intrinsic (RNE, emits v_cvt_pk_bf16_f32)
__device__ __forceinline__ unsigned int pk2(float a, float b) {
  union { __hip_bfloat162 h; unsigned int u; } c;
  c.h = __float22bfloat162_rn(make_float2(a, b));
  return c.u;
}
__device__ __forceinline__ float bflo(unsigned int u) {
  union { unsigned int i; float f; } x; x.i = u << 16; return x.f;
}
__device__ __forceinline__ float bfhi(unsigned int u) {
  union { unsigned int i; float f; } x; x.i = u & 0xffff0000u; return x.f;
}
// guaranteed single-instruction 2^x (v_exp_f32); 1-src/1-dst asm fallback
__device__ __forceinline__ float exp2_raw(float x) {
#if __has_builtin(__builtin_amdgcn_exp2f)
  return __builtin_amdgcn_exp2f(x);
#else
  float r; asm("v_exp_f32 %0, %1" : "=v"(r) : "v"(x)); return r;
#endif
}
__device__ __forceinline__ f32x16 fzero16() {
  f32x16 z;
#pragma unroll
  for (int i = 0; i < 16; ++i) z[i] = 0.f;
  return z;
}
__device__ __forceinline__ void ld16(const float* p, float* f) {
#pragma unroll
  for (int i = 0; i < 4; ++i) {
    float4 a = *(const float4*)(p + 4 * i);
    f[4*i] = a.x; f[4*i+1] = a.y; f[4*i+2] = a.z; f[4*i+3] = a.w;
  }
}
__device__ __forceinline__ void ld8f(const float* p, float* f) {
  float4 a = *(const float4*)p, b = *(const float4*)(p + 4);
  f[0]=a.x; f[1]=a.y; f[2]=a.z; f[3]=a.w; f[4]=b.x; f[5]=b.y; f[6]=b.z; f[7]=b.w;
}

// 1/sqrt(16) * log2(e): folded into Q so attention works in log2 domain
#define QSC 0.3606737602f

// ---------------- W: fp32 -> bf16 weight conversion ----------------
__global__ __launch_bounds__(256) void k_cvtw(
    const float* __restrict__ wil, const float* __restrict__ wol,
    const float* __restrict__ wis, const float* __restrict__ wos,
    short* __restrict__ o) {
  const int idx = (blockIdx.x * 256 + threadIdx.x) * 8;
  const float* src; int off;
  if (idx < 49152)       { src = wil; off = idx; }
  else if (idx < 65536)  { src = wol; off = idx - 49152; }
  else if (idx < 114688) { src = wis; off = idx - 65536; }
  else                   { src = wos; off = idx - 114688; }
  float f[8];
  ld8f(src + off, f);
  short8 r;
#pragma unroll
  for (int j = 0; j < 8; ++j) r[j] = f2bfs(f[j]);
  *(short8*)(o + idx) = r;
}

// ---------------- K1: long QKV projection, MFMA ----------------
// Emits bf16 Q/K/V [pair=b*8+hh][l][d] and pos_ct[c][tok] bf16.
// Stager (r13 layout): thread = (c, h-row), 16 consecutive w-pixels = 64B/lane.
__global__ __launch_bounds__(256) void k_proj_long(
    const float* __restrict__ q, const float* __restrict__ k,
    const float* __restrict__ v, const float* __restrict__ pq,
    const float* __restrict__ pk,
    const short* __restrict__ wbf, const float* __restrict__ b_in,
    short* __restrict__ qb, short* __restrict__ kb, short* __restrict__ vb,
    short* __restrict__ pos_ct) {
  __shared__ short XQ[32][132], XK[32][132], XV[32][132];
  const int tid = threadIdx.x;
  const int wid = tid >> 6, lane = tid & 63;
  const int l31 = lane & 31, g = lane >> 5;
  const int tok0 = blockIdx.x * 32;
  const int l = tok0 >> 9, b0 = tok0 & 511;
  const int t = l >> 4, bh = (l >> 2) & 3, bw = l & 3;
  const int nb = b0 >> 8, ph0 = (b0 >> 4) & 15;
  {
    const int c = tid >> 1, half = tid & 1;
    const int h = bh * 16 + ph0 + half, w0 = bw * 16;
    const size_t gb = (((size_t)(nb * CC + c) * 4 + t) << 12) + h * 64 + w0;
    float a[16], p[16];
    ld16(q + gb, a); ld16(pq + gb, p);
    {
      short8 s0, s1;
#pragma unroll
      for (int j = 0; j < 8; ++j) { s0[j] = f2bfs(p[j]); s1[j] = f2bfs(p[8 + j]); }
      short* pd = pos_ct + (size_t)c * 32768 + tok0 + half * 16;
      *(short8*)pd = s0;
      *(short8*)(pd + 8) = s1;
    }
#pragma unroll
    for (int j = 0; j < 16; ++j) XQ[half * 16 + j][c] = f2bfs(a[j] + p[j]);
    ld16(k + gb, a); ld16(pk + gb, p);
#pragma unroll
    for (int j = 0; j < 16; ++j) XK[half * 16 + j][c] = f2bfs(a[j] + p[j]);
    ld16(v + gb, a);
#pragma unroll
    for (int j = 0; j < 16; ++j) XV[half * 16 + j][c] = f2bfs(a[j]);
  }
  __syncthreads();
  for (int i = 0; i < 3; ++i) {
    const int nt = wid + 4 * i;
    const int nch = nt * 32 + l31;
    const int which = nt >> 2;
    const short (*X)[132] = (which == 0) ? XQ : (which == 1) ? XK : XV;
    f32x16 acc = fzero16();
#pragma unroll
    for (int k0 = 0; k0 < 128; k0 += 16) {
      I4S8 af;
      af.h[0] = *(const int2*)&X[l31][k0 + 8 * g];
      af.h[1] = *(const int2*)&X[l31][k0 + 8 * g + 4];
      short8 bf = *(const short8*)(wbf + nch * CC + k0 + 8 * g);
      acc = __builtin_amdgcn_mfma_f32_32x32x16_bf16(af.s, bf, acc, 0, 0, 0);
    }
    const float bias = b_in[nch];
    const int hh = (nch >> 4) & 7, d = nch & 15;
    short* dst = (which == 0) ? qb : (which == 1) ? kb : vb;
    const float sc = (which == 0) ? QSC : 1.0f;
#pragma unroll
    for (int r = 0; r < 16; ++r) {
      const int tt = (r & 3) + 8 * (r >> 2) + 4 * g;
      dst[((size_t)((b0 + tt) * 8 + hh) * 64 + l) * 16 + d] =
          f2bfs((acc[r] + bias) * sc);
    }
  }
}

// ---------------- K2: unified MFMA flash attention ----------------
// Q64/wave, optional split-K (static-max exp2 makes partials additive).
// r13 single-buffer V^T LDS tile [17][36] (ones row 16 -> acc[8]=lsum),
// unroll-2 key loop, + s_setprio(1) around MFMA clusters (T5).
template<int SEQ, int BATCH, int SPLITK>
__global__ __launch_bounds__(256) void k_attn(
    const short* __restrict__ qsp, const short* __restrict__ ksp,
    const short* __restrict__ vsp, short* __restrict__ ao) {
  __shared__ short vt[4][17 * 36];
  __shared__ float comb[2][64][19];   // used only when SPLITK==2
  const int tid = threadIdx.x;
  const int wid = tid >> 6, lane = tid & 63;
  const int l31 = lane & 31, g = lane >> 5;
  constexpr int QG = SEQ / 64;
  constexpr int NBLK = (BATCH * 8 * QG * SPLITK) / 4;
  // XCD-chunk swizzle (bijective: NBLK % 8 == 0)
  const int blk = (blockIdx.x & 7) * (NBLK / 8) + (blockIdx.x >> 3);
  const int gw = blk * 4 + wid;
  const int kh = (SPLITK == 2) ? (gw & 1) : 0;
  const int rest = (SPLITK == 2) ? (gw >> 1) : gw;
  const int pair = rest / QG;
  const int q0 = (rest % QG) * 64;
  const int batch = pair >> 3, hh = pair & 7;
  const size_t pbase = (size_t)pair * (SEQ * 16);
  short* vtw = &vt[wid][0];
  // ones row (A rows 16..31): 18 lanes write one b32 each, once
  if (lane < 18) *(int*)(vtw + 16 * 36 + 2 * lane) = 0x3F803F80;

  const short8 qf0 = *(const short8*)(qsp + pbase + (size_t)(q0 + l31) * 16 + 8 * g);
  const short8 qf1 = *(const short8*)(qsp + pbase + (size_t)(q0 + 32 + l31) * 16 + 8 * g);

  f32x16 acc0 = fzero16(), acc1 = fzero16();
  const int arow = (l31 < 16) ? l31 : 16;
  const short* vtr = vtw + arow * 36;
  const int kbeg = kh * (SEQ / SPLITK), kend = kbeg + SEQ / SPLITK;

#pragma unroll 2
  for (int k0 = kbeg; k0 < kend; k0 += 32) {
    const short8 kf = *(const short8*)(ksp + pbase + (size_t)(k0 + l31) * 16 + 8 * g);
    const short8 vf = *(const short8*)(vsp + pbase + (size_t)(k0 + l31) * 16 + 8 * g);
#pragma unroll
    for (int j = 0; j < 8; ++j)
      vtw[(8 * g + j) * 36 + l31] = vf[j];

    __builtin_amdgcn_s_setprio(1);
    f32x16 s0 = __builtin_amdgcn_mfma_f32_32x32x16_bf16(kf, qf0, fzero16(), 0, 0, 0);
    f32x16 s1 = __builtin_amdgcn_mfma_f32_32x32x16_bf16(kf, qf1, fzero16(), 0, 0, 0);
    __builtin_amdgcn_s_setprio(0);

    I4S8 pa0, pb0, pa1, pb1;
#pragma unroll
    for (int j = 0; j < 4; ++j) {
      pa0.i[j] = (int)pk2(exp2_raw(s0[2 * j]), exp2_raw(s0[2 * j + 1]));
      pb0.i[j] = (int)pk2(exp2_raw(s0[8 + 2 * j]), exp2_raw(s0[9 + 2 * j]));
    }
#pragma unroll
    for (int j = 0; j < 4; ++j) {
      pa1.i[j] = (int)pk2(exp2_raw(s1[2 * j]), exp2_raw(s1[2 * j + 1]));
      pb1.i[j] = (int)pk2(exp2_raw(s1[8 + 2 * j]), exp2_raw(s1[9 + 2 * j]));
    }

    I4S8 a1, a2;
    a1.h[0] = *(const int2*)(vtr + 4 * g);
    a1.h[1] = *(const int2*)(vtr + 8 + 4 * g);
    a2.h[0] = *(const int2*)(vtr + 16 + 4 * g);
    a2.h[1] = *(const int2*)(vtr + 24 + 4 * g);
    __builtin_amdgcn_s_setprio(1);
    acc0 = __builtin_amdgcn_mfma_f32_32x32x16_bf16(a1.s, pa0.s, acc0, 0, 0, 0);
    acc0 = __builtin_amdgcn_mfma_f32_32x32x16_bf16(a2.s, pb0.s, acc0, 0, 0, 0);
    acc1 = __builtin_amdgcn_mfma_f32_32x32x16_bf16(a1.s, pa1.s, acc1, 0, 0, 0);
    acc1 = __builtin_amdgcn_mfma_f32_32x32x16_bf16(a2.s, pb1.s, acc1, 0, 0, 0);
    __builtin_amdgcn_s_setprio(0);
  }

  if (SPLITK == 2) {
    // split-K combine: kh=1 deposits 18 partials/lane; kh=0 adds
    const int pi = wid >> 1;
    if (kh == 1) {
#pragma unroll
      for (int r = 0; r < 9; ++r) {
        comb[pi][lane][r] = acc0[r];
        comb[pi][lane][9 + r] = acc1[r];
      }
    }
    __syncthreads();
    if (kh == 1) return;
#pragma unroll
    for (int r = 0; r < 9; ++r) {
      acc0[r] += comb[pi][lane][r];
      acc1[r] += comb[pi][lane][9 + r];
    }
  }

  const float inv0 = 1.0f / acc0[8];   // ones-row accumulation = full lsum
  const float inv1 = 1.0f / acc1[8];
  const int qi = q0 + l31;
  short* dst0 = ao + ((size_t)qi * BATCH + batch) * CC + hh * 16 + 4 * g;
  short* dst1 = ao + ((size_t)(qi + 32) * BATCH + batch) * CC + hh * 16 + 4 * g;
  uint2 o1, o2;
  o1.x = pk2(acc0[0] * inv0, acc0[1] * inv0);
  o1.y = pk2(acc0[2] * inv0, acc0[3] * inv0);
  o2.x = pk2(acc0[4] * inv0, acc0[5] * inv0);
  o2.y = pk2(acc0[6] * inv0, acc0[7] * inv0);
  *(uint2*)dst0 = o1;
  *(uint2*)(dst0 + 8) = o2;
  o1.x = pk2(acc1[0] * inv1, acc1[1] * inv1);
  o1.y = pk2(acc1[2] * inv1, acc1[3] * inv1);
  o2.x = pk2(acc1[4] * inv1, acc1[5] * inv1);
  o2.y = pk2(acc1[6] * inv1, acc1[7] * inv1);
  *(uint2*)dst1 = o1;
  *(uint2*)(dst1 + 8) = o2;
}

// ---------------- K3: long out-proj + pos + short QKV proj (MFMA x2) ----------------
__global__ __launch_bounds__(256) void k_mid(
    const short* __restrict__ ao, const short* __restrict__ pos_ct,
    const short* __restrict__ wobf, const float* __restrict__ b_out_l,
    const short* __restrict__ wibf, const float* __restrict__ b_in_s,
    short* __restrict__ qb, short* __restrict__ kb, short* __restrict__ vb) {
  __shared__ short YQK[32][132], YV[32][132];
  const int tid = threadIdx.x;
  const int wid = tid >> 6, lane = tid & 63;
  const int l31 = lane & 31, g = lane >> 5;
  const int tok0 = blockIdx.x * 32;
  const int l = tok0 >> 9, b0 = tok0 & 511;
  const int t = l >> 4, bh = (l >> 2) & 3, bw = l & 3;
  const int nb = b0 >> 8, ph0 = (b0 >> 4) & 15;
  {
    const int nch = wid * 32 + l31;
    f32x16 acc = fzero16();
#pragma unroll
    for (int k0 = 0; k0 < 128; k0 += 16) {
      short8 af = *(const short8*)(ao + (size_t)(tok0 + l31) * CC + k0 + 8 * g);
      short8 bf = *(const short8*)(wobf + nch * CC + k0 + 8 * g);
      acc = __builtin_amdgcn_mfma_f32_32x32x16_bf16(af, bf, acc, 0, 0, 0);
    }
    const float bias = b_out_l[nch];
    float pos[16];
#pragma unroll
    for (int rr = 0; rr < 4; ++rr) {
      int2 pp = *(const int2*)(pos_ct + (size_t)nch * 32768 + tok0 + rr * 8 + 4 * g);
      pos[rr * 4 + 0] = bflo((unsigned int)pp.x);
      pos[rr * 4 + 1] = bfhi((unsigned int)pp.x);
      pos[rr * 4 + 2] = bflo((unsigned int)pp.y);
      pos[rr * 4 + 3] = bfhi((unsigned int)pp.y);
    }
#pragma unroll
    for (int r = 0; r < 16; ++r) {
      const int tt = (r & 3) + 8 * (r >> 2) + 4 * g;
      const float y = acc[r] + bias;
      YV[tt][nch] = f2bfs(y);
      YQK[tt][nch] = f2bfs(y + pos[r]);
    }
  }
  __syncthreads();
  const int bs = nb * 16 + bh * 4 + bw;
  const int ls0 = (t * 16 + ph0) * 16;
  for (int i = 0; i < 3; ++i) {
    const int nt = wid + 4 * i;
    const int nch = nt * 32 + l31;
    const int which = nt >> 2;
    const short (*X)[132] = (which == 2) ? YV : YQK;
    f32x16 acc = fzero16();
#pragma unroll
    for (int k0 = 0; k0 < 128; k0 += 16) {
      I4S8 af;
      af.h[0] = *(const int2*)&X[l31][k0 + 8 * g];
      af.h[1] = *(const int2*)&X[l31][k0 + 8 * g + 4];
      short8 bf = *(const short8*)(wibf + nch * CC + k0 + 8 * g);
      acc = __builtin_amdgcn_mfma_f32_32x32x16_bf16(af.s, bf, acc, 0, 0, 0);
    }
    const float bias = b_in_s[nch];
    const int hh = (nch >> 4) & 7, d = nch & 15;
    short* dst = (which == 0) ? qb : (which == 1) ? kb : vb;
    const float sc = (which == 0) ? QSC : 1.0f;
    const size_t base = ((size_t)(bs * 8 + hh) * 1024 + ls0) * 16 + d;
#pragma unroll
    for (int r = 0; r < 16; ++r) {
      const int tt = (r & 3) + 8 * (r >> 2) + 4 * g;
      dst[base + (size_t)tt * 16] = f2bfs((acc[r] + bias) * sc);
    }
  }
}

// ---------------- K4: short out-proj + scatter to (N,C,T,H,W) fp32, MFMA ----------------
__global__ __launch_bounds__(256) void k_out_short(
    const short* __restrict__ ao, const short* __restrict__ wbf,
    const float* __restrict__ b_out, float* __restrict__ out) {
  const int tid = threadIdx.x;
  const int wid = tid >> 6, lane = tid & 63;
  const int l31 = lane & 31, g = lane >> 5;
  const int bs = blockIdx.x & 31;
  const int qi0 = (blockIdx.x >> 5) << 5;
  const int nb = bs >> 4, bh = (bs >> 2) & 3, bw = bs & 3;
  const int t = qi0 >> 8, ph0 = (qi0 >> 4) & 15;
  const int nch = wid * 32 + l31;
  f32x16 acc = fzero16();
#pragma unroll
  for (int k0 = 0; k0 < 128; k0 += 16) {
    short8 af = *(const short8*)(ao + ((size_t)(qi0 + l31) * 32 + bs) * CC + k0 + 8 * g);
    short8 bf = *(const short8*)(wbf + nch * CC + k0 + 8 * g);
    acc = __builtin_amdgcn_mfma_f32_32x32x16_bf16(af, bf, acc, 0, 0, 0);
  }
  const float bias = b_out[nch];
#pragma unroll
  for (int rr = 0; rr < 4; ++rr) {
    const int tt0 = rr * 8 + 4 * g;
    const int ph_off = tt0 >> 4, pw = tt0 & 15;
    const int h = bh * 16 + ph0 + ph_off, w = bw * 16 + pw;
    const size_t adr = (((size_t)(nb * CC + nch) * 4 + t) << 12) + h * 64 + w;
    float4 f;
    f.x = acc[rr * 4 + 0] + bias; f.y = acc[rr * 4 + 1] + bias;
    f.z = acc[rr * 4 + 2] + bias; f.w = acc[rr * 4 + 3] + bias;
    *(float4*)(out + adr) = f;
  }
}

extern "C" void kernel_launch(void* const* d_in, const int* in_sizes, int n_in,
                              void* d_out, int out_size, void* d_ws, size_t ws_size,
                              hipStream_t stream) {
  (void)in_sizes; (void)n_in; (void)out_size; (void)ws_size;
  const float* q   = (const float*)d_in[0];
  const float* k   = (const float*)d_in[1];
  const float* v   = (const float*)d_in[2];
  const float* pq  = (const float*)d_in[3];
  const float* pk  = (const float*)d_in[4];
  const float* wil = (const float*)d_in[5];
  const float* bil = (const float*)d_in[6];
  const float* wol = (const float*)d_in[7];
  const float* bol = (const float*)d_in[8];
  const float* wis = (const float*)d_in[9];
  const float* bis = (const float*)d_in[10];
  const float* wos = (const float*)d_in[11];
  const float* bos = (const float*)d_in[12];

  short* qs     = (short*)d_ws;            // 4.19M shorts each region
  short* ksb    = qs + 4194304;
  short* vsb    = ksb + 4194304;
  short* ao     = vsb + 4194304;
  short* pos_ct = ao + 4194304;
  short* wbf    = pos_ct + 4194304;        // 131072 shorts

  k_cvtw<<<dim3(64), dim3(256), 0, stream>>>(wil, wol, wis, wos, wbf);
  k_proj_long<<<dim3(1024), dim3(256), 0, stream>>>(q, k, v, pq, pk, wbf, bil,
                                                    qs, ksb, vsb, pos_ct);
  k_attn<64, 512, 1><<<dim3(1024), dim3(256), 0, stream>>>(qs, ksb, vsb, ao);
  k_mid<<<dim3(1024), dim3(256), 0, stream>>>(ao, pos_ct, wbf + 49152, bol,
                                              wbf + 65536, bis, qs, ksb, vsb);
  k_attn<1024, 32, 2><<<dim3(2048), dim3(256), 0, stream>>>(qs, ksb, vsb, ao);
  k_out_short<<<dim3(1024), dim3(256), 0, stream>>>(ao, wbf + 114688, bos,
                                                    (float*)d_out);
}

// Round 16
// 140.879 us; speedup vs baseline: 1.0348x; 1.0014x over previous
//
#include <hip/hip_runtime.h>
#include <hip/hip_bf16.h>

#define CC 128

typedef __attribute__((ext_vector_type(8))) short short8;
typedef __attribute__((ext_vector_type(16))) float f32x16;

union I4S8 { int4 i; short8 s; int2 h[2]; };

__device__ __forceinline__ unsigned short f2bfu(float f) {
  union { float f; unsigned int i; } x; x.f = f;
  unsigned int r = x.i + 0x7fffu + ((x.i >> 16) & 1u);
  return (unsigned short)(r >> 16);
}
__device__ __forceinline__ short f2bfs(float f) { return (short)f2bfu(f); }
// packed f32x2 -> bf16x2 via compiler intrinsic (RNE, emits v_cvt_pk_bf16_f32)
__device__ __forceinline__ unsigned int pk2(float a, float b) {
  union { __hip_bfloat162 h; unsigned int u; } c;
  c.h = __float22bfloat162_rn(make_float2(a, b));
  return c.u;
}
__device__ __forceinline__ float bflo(unsigned int u) {
  union { unsigned int i; float f; } x; x.i = u << 16; return x.f;
}
__device__ __forceinline__ float bfhi(unsigned int u) {
  union { unsigned int i; float f; } x; x.i = u & 0xffff0000u; return x.f;
}
// guaranteed single-instruction 2^x (v_exp_f32); 1-src/1-dst asm fallback
__device__ __forceinline__ float exp2_raw(float x) {
#if __has_builtin(__builtin_amdgcn_exp2f)
  return __builtin_amdgcn_exp2f(x);
#else
  float r; asm("v_exp_f32 %0, %1" : "=v"(r) : "v"(x)); return r;
#endif
}
__device__ __forceinline__ f32x16 fzero16() {
  f32x16 z;
#pragma unroll
  for (int i = 0; i < 16; ++i) z[i] = 0.f;
  return z;
}
__device__ __forceinline__ void ld16(const float* p, float* f) {
#pragma unroll
  for (int i = 0; i < 4; ++i) {
    float4 a = *(const float4*)(p + 4 * i);
    f[4*i] = a.x; f[4*i+1] = a.y; f[4*i+2] = a.z; f[4*i+3] = a.w;
  }
}
__device__ __forceinline__ void ld8f(const float* p, float* f) {
  float4 a = *(const float4*)p, b = *(const float4*)(p + 4);
  f[0]=a.x; f[1]=a.y; f[2]=a.z; f[3]=a.w; f[4]=b.x; f[5]=b.y; f[6]=b.z; f[7]=b.w;
}

// 1/sqrt(16) * log2(e): folded into Q so attention works in log2 domain
#define QSC 0.3606737602f

// ---------------- W: fp32 -> bf16 weight conversion ----------------
__global__ __launch_bounds__(256) void k_cvtw(
    const float* __restrict__ wil, const float* __restrict__ wol,
    const float* __restrict__ wis, const float* __restrict__ wos,
    short* __restrict__ o) {
  const int idx = (blockIdx.x * 256 + threadIdx.x) * 8;
  const float* src; int off;
  if (idx < 49152)       { src = wil; off = idx; }
  else if (idx < 65536)  { src = wol; off = idx - 49152; }
  else if (idx < 114688) { src = wis; off = idx - 65536; }
  else                   { src = wos; off = idx - 114688; }
  float f[8];
  ld8f(src + off, f);
  short8 r;
#pragma unroll
  for (int j = 0; j < 8; ++j) r[j] = f2bfs(f[j]);
  *(short8*)(o + idx) = r;
}

// ---------------- K1: long QKV projection, MFMA ----------------
// Emits bf16 Q/K/V [pair=b*8+hh][l][d] and pos_ct[c][tok] bf16.
// Stager: thread = (c, h-row), 16 consecutive w-pixels = 64B/lane.
__global__ __launch_bounds__(256) void k_proj_long(
    const float* __restrict__ q, const float* __restrict__ k,
    const float* __restrict__ v, const float* __restrict__ pq,
    const float* __restrict__ pk,
    const short* __restrict__ wbf, const float* __restrict__ b_in,
    short* __restrict__ qb, short* __restrict__ kb, short* __restrict__ vb,
    short* __restrict__ pos_ct) {
  __shared__ short XQ[32][132], XK[32][132], XV[32][132];
  const int tid = threadIdx.x;
  const int wid = tid >> 6, lane = tid & 63;
  const int l31 = lane & 31, g = lane >> 5;
  const int tok0 = blockIdx.x * 32;
  const int l = tok0 >> 9, b0 = tok0 & 511;
  const int t = l >> 4, bh = (l >> 2) & 3, bw = l & 3;
  const int nb = b0 >> 8, ph0 = (b0 >> 4) & 15;
  {
    const int c = tid >> 1, half = tid & 1;
    const int h = bh * 16 + ph0 + half, w0 = bw * 16;
    const size_t gb = (((size_t)(nb * CC + c) * 4 + t) << 12) + h * 64 + w0;
    float a[16], p[16];
    ld16(q + gb, a); ld16(pq + gb, p);
    {
      short8 s0, s1;
#pragma unroll
      for (int j = 0; j < 8; ++j) { s0[j] = f2bfs(p[j]); s1[j] = f2bfs(p[8 + j]); }
      short* pd = pos_ct + (size_t)c * 32768 + tok0 + half * 16;
      *(short8*)pd = s0;
      *(short8*)(pd + 8) = s1;
    }
#pragma unroll
    for (int j = 0; j < 16; ++j) XQ[half * 16 + j][c] = f2bfs(a[j] + p[j]);
    ld16(k + gb, a); ld16(pk + gb, p);
#pragma unroll
    for (int j = 0; j < 16; ++j) XK[half * 16 + j][c] = f2bfs(a[j] + p[j]);
    ld16(v + gb, a);
#pragma unroll
    for (int j = 0; j < 16; ++j) XV[half * 16 + j][c] = f2bfs(a[j]);
  }
  __syncthreads();
  for (int i = 0; i < 3; ++i) {
    const int nt = wid + 4 * i;
    const int nch = nt * 32 + l31;
    const int which = nt >> 2;
    const short (*X)[132] = (which == 0) ? XQ : (which == 1) ? XK : XV;
    f32x16 acc = fzero16();
#pragma unroll
    for (int k0 = 0; k0 < 128; k0 += 16) {
      I4S8 af;
      af.h[0] = *(const int2*)&X[l31][k0 + 8 * g];
      af.h[1] = *(const int2*)&X[l31][k0 + 8 * g + 4];
      short8 bf = *(const short8*)(wbf + nch * CC + k0 + 8 * g);
      acc = __builtin_amdgcn_mfma_f32_32x32x16_bf16(af.s, bf, acc, 0, 0, 0);
    }
    const float bias = b_in[nch];
    const int hh = (nch >> 4) & 7, d = nch & 15;
    short* dst = (which == 0) ? qb : (which == 1) ? kb : vb;
    const float sc = (which == 0) ? QSC : 1.0f;
#pragma unroll
    for (int r = 0; r < 16; ++r) {
      const int tt = (r & 3) + 8 * (r >> 2) + 4 * g;
      dst[((size_t)((b0 + tt) * 8 + hh) * 64 + l) * 16 + d] =
          f2bfs((acc[r] + bias) * sc);
    }
  }
}

// ---------------- K2: unified MFMA flash attention ----------------
// Q64/wave, optional split-K (static-max exp2 makes partials additive).
// Single-buffer V^T LDS tile [17][36] (ones row 16 -> acc[8]=lsum),
// unroll-2 key loop, s_setprio around MFMA clusters.
template<int SEQ, int BATCH, int SPLITK>
__global__ __launch_bounds__(256) void k_attn(
    const short* __restrict__ qsp, const short* __restrict__ ksp,
    const short* __restrict__ vsp, short* __restrict__ ao) {
  __shared__ short vt[4][17 * 36];
  __shared__ float comb[2][64][19];   // used only when SPLITK==2
  const int tid = threadIdx.x;
  const int wid = tid >> 6, lane = tid & 63;
  const int l31 = lane & 31, g = lane >> 5;
  constexpr int QG = SEQ / 64;
  constexpr int NBLK = (BATCH * 8 * QG * SPLITK) / 4;
  // XCD-chunk swizzle (bijective: NBLK % 8 == 0)
  const int blk = (blockIdx.x & 7) * (NBLK / 8) + (blockIdx.x >> 3);
  const int gw = blk * 4 + wid;
  const int kh = (SPLITK == 2) ? (gw & 1) : 0;
  const int rest = (SPLITK == 2) ? (gw >> 1) : gw;
  const int pair = rest / QG;
  const int q0 = (rest % QG) * 64;
  const int batch = pair >> 3, hh = pair & 7;
  const size_t pbase = (size_t)pair * (SEQ * 16);
  short* vtw = &vt[wid][0];
  // ones row (A rows 16..31): 18 lanes write one b32 each, once
  if (lane < 18) *(int*)(vtw + 16 * 36 + 2 * lane) = 0x3F803F80;

  const short8 qf0 = *(const short8*)(qsp + pbase + (size_t)(q0 + l31) * 16 + 8 * g);
  const short8 qf1 = *(const short8*)(qsp + pbase + (size_t)(q0 + 32 + l31) * 16 + 8 * g);

  f32x16 acc0 = fzero16(), acc1 = fzero16();
  const int arow = (l31 < 16) ? l31 : 16;
  const short* vtr = vtw + arow * 36;
  const int kbeg = kh * (SEQ / SPLITK), kend = kbeg + SEQ / SPLITK;

#pragma unroll 2
  for (int k0 = kbeg; k0 < kend; k0 += 32) {
    const short8 kf = *(const short8*)(ksp + pbase + (size_t)(k0 + l31) * 16 + 8 * g);
    const short8 vf = *(const short8*)(vsp + pbase + (size_t)(k0 + l31) * 16 + 8 * g);
#pragma unroll
    for (int j = 0; j < 8; ++j)
      vtw[(8 * g + j) * 36 + l31] = vf[j];

    __builtin_amdgcn_s_setprio(1);
    f32x16 s0 = __builtin_amdgcn_mfma_f32_32x32x16_bf16(kf, qf0, fzero16(), 0, 0, 0);
    f32x16 s1 = __builtin_amdgcn_mfma_f32_32x32x16_bf16(kf, qf1, fzero16(), 0, 0, 0);
    __builtin_amdgcn_s_setprio(0);

    I4S8 pa0, pb0, pa1, pb1;
#pragma unroll
    for (int j = 0; j < 4; ++j) {
      pa0.i[j] = (int)pk2(exp2_raw(s0[2 * j]), exp2_raw(s0[2 * j + 1]));
      pb0.i[j] = (int)pk2(exp2_raw(s0[8 + 2 * j]), exp2_raw(s0[9 + 2 * j]));
    }
#pragma unroll
    for (int j = 0; j < 4; ++j) {
      pa1.i[j] = (int)pk2(exp2_raw(s1[2 * j]), exp2_raw(s1[2 * j + 1]));
      pb1.i[j] = (int)pk2(exp2_raw(s1[8 + 2 * j]), exp2_raw(s1[9 + 2 * j]));
    }

    I4S8 a1, a2;
    a1.h[0] = *(const int2*)(vtr + 4 * g);
    a1.h[1] = *(const int2*)(vtr + 8 + 4 * g);
    a2.h[0] = *(const int2*)(vtr + 16 + 4 * g);
    a2.h[1] = *(const int2*)(vtr + 24 + 4 * g);
    __builtin_amdgcn_s_setprio(1);
    acc0 = __builtin_amdgcn_mfma_f32_32x32x16_bf16(a1.s, pa0.s, acc0, 0, 0, 0);
    acc0 = __builtin_amdgcn_mfma_f32_32x32x16_bf16(a2.s, pb0.s, acc0, 0, 0, 0);
    acc1 = __builtin_amdgcn_mfma_f32_32x32x16_bf16(a1.s, pa1.s, acc1, 0, 0, 0);
    acc1 = __builtin_amdgcn_mfma_f32_32x32x16_bf16(a2.s, pb1.s, acc1, 0, 0, 0);
    __builtin_amdgcn_s_setprio(0);
  }

  if (SPLITK == 2) {
    // split-K combine: kh=1 deposits 18 partials/lane; kh=0 adds
    const int pi = wid >> 1;
    if (kh == 1) {
#pragma unroll
      for (int r = 0; r < 9; ++r) {
        comb[pi][lane][r] = acc0[r];
        comb[pi][lane][9 + r] = acc1[r];
      }
    }
    __syncthreads();
    if (kh == 1) return;
#pragma unroll
    for (int r = 0; r < 9; ++r) {
      acc0[r] += comb[pi][lane][r];
      acc1[r] += comb[pi][lane][9 + r];
    }
  }

  const float inv0 = 1.0f / acc0[8];   // ones-row accumulation = full lsum
  const float inv1 = 1.0f / acc1[8];
  const int qi = q0 + l31;
  short* dst0 = ao + ((size_t)qi * BATCH + batch) * CC + hh * 16 + 4 * g;
  short* dst1 = ao + ((size_t)(qi + 32) * BATCH + batch) * CC + hh * 16 + 4 * g;
  uint2 o1, o2;
  o1.x = pk2(acc0[0] * inv0, acc0[1] * inv0);
  o1.y = pk2(acc0[2] * inv0, acc0[3] * inv0);
  o2.x = pk2(acc0[4] * inv0, acc0[5] * inv0);
  o2.y = pk2(acc0[6] * inv0, acc0[7] * inv0);
  *(uint2*)dst0 = o1;
  *(uint2*)(dst0 + 8) = o2;
  o1.x = pk2(acc1[0] * inv1, acc1[1] * inv1);
  o1.y = pk2(acc1[2] * inv1, acc1[3] * inv1);
  o2.x = pk2(acc1[4] * inv1, acc1[5] * inv1);
  o2.y = pk2(acc1[6] * inv1, acc1[7] * inv1);
  *(uint2*)dst1 = o1;
  *(uint2*)(dst1 + 8) = o2;
}

// ---------------- K3: long out-proj + pos + short QKV proj (MFMA x2) ----------------
__global__ __launch_bounds__(256) void k_mid(
    const short* __restrict__ ao, const short* __restrict__ pos_ct,
    const short* __restrict__ wobf, const float* __restrict__ b_out_l,
    const short* __restrict__ wibf, const float* __restrict__ b_in_s,
    short* __restrict__ qb, short* __restrict__ kb, short* __restrict__ vb) {
  __shared__ short YQK[32][132], YV[32][132];
  const int tid = threadIdx.x;
  const int wid = tid >> 6, lane = tid & 63;
  const int l31 = lane & 31, g = lane >> 5;
  const int tok0 = blockIdx.x * 32;
  const int l = tok0 >> 9, b0 = tok0 & 511;
  const int t = l >> 4, bh = (l >> 2) & 3, bw = l & 3;
  const int nb = b0 >> 8, ph0 = (b0 >> 4) & 15;
  {
    const int nch = wid * 32 + l31;
    f32x16 acc = fzero16();
#pragma unroll
    for (int k0 = 0; k0 < 128; k0 += 16) {
      short8 af = *(const short8*)(ao + (size_t)(tok0 + l31) * CC + k0 + 8 * g);
      short8 bf = *(const short8*)(wobf + nch * CC + k0 + 8 * g);
      acc = __builtin_amdgcn_mfma_f32_32x32x16_bf16(af, bf, acc, 0, 0, 0);
    }
    const float bias = b_out_l[nch];
    float pos[16];
#pragma unroll
    for (int rr = 0; rr < 4; ++rr) {
      int2 pp = *(const int2*)(pos_ct + (size_t)nch * 32768 + tok0 + rr * 8 + 4 * g);
      pos[rr * 4 + 0] = bflo((unsigned int)pp.x);
      pos[rr * 4 + 1] = bfhi((unsigned int)pp.x);
      pos[rr * 4 + 2] = bflo((unsigned int)pp.y);
      pos[rr * 4 + 3] = bfhi((unsigned int)pp.y);
    }
#pragma unroll
    for (int r = 0; r < 16; ++r) {
      const int tt = (r & 3) + 8 * (r >> 2) + 4 * g;
      const float y = acc[r] + bias;
      YV[tt][nch] = f2bfs(y);
      YQK[tt][nch] = f2bfs(y + pos[r]);
    }
  }
  __syncthreads();
  const int bs = nb * 16 + bh * 4 + bw;
  const int ls0 = (t * 16 + ph0) * 16;
  for (int i = 0; i < 3; ++i) {
    const int nt = wid + 4 * i;
    const int nch = nt * 32 + l31;
    const int which = nt >> 2;
    const short (*X)[132] = (which == 2) ? YV : YQK;
    f32x16 acc = fzero16();
#pragma unroll
    for (int k0 = 0; k0 < 128; k0 += 16) {
      I4S8 af;
      af.h[0] = *(const int2*)&X[l31][k0 + 8 * g];
      af.h[1] = *(const int2*)&X[l31][k0 + 8 * g + 4];
      short8 bf = *(const short8*)(wibf + nch * CC + k0 + 8 * g);
      acc = __builtin_amdgcn_mfma_f32_32x32x16_bf16(af.s, bf, acc, 0, 0, 0);
    }
    const float bias = b_in_s[nch];
    const int hh = (nch >> 4) & 7, d = nch & 15;
    short* dst = (which == 0) ? qb : (which == 1) ? kb : vb;
    const float sc = (which == 0) ? QSC : 1.0f;
    const size_t base = ((size_t)(bs * 8 + hh) * 1024 + ls0) * 16 + d;
#pragma unroll
    for (int r = 0; r < 16; ++r) {
      const int tt = (r & 3) + 8 * (r >> 2) + 4 * g;
      dst[base + (size_t)tt * 16] = f2bfs((acc[r] + bias) * sc);
    }
  }
}

// ---------------- K4: short out-proj + scatter, MFMA (swapped operands) ----------------
// C^T = mfma(W, AO): lane = token, regs = 16 channels. Stores become
// 4x64B-contiguous segments per instruction (lanes sweep w pixels) instead of
// 64x16B (lanes sweeping the 16KB-strided channel axis).
__global__ __launch_bounds__(256) void k_out_short(
    const short* __restrict__ ao, const short* __restrict__ wbf,
    const float* __restrict__ b_out, float* __restrict__ out) {
  const int tid = threadIdx.x;
  const int wid = tid >> 6, lane = tid & 63;
  const int l31 = lane & 31, g = lane >> 5;
  const int bs = blockIdx.x & 31;
  const int qi0 = (blockIdx.x >> 5) << 5;
  const int nb = bs >> 4, bh = (bs >> 2) & 3, bw = bs & 3;
  const int t = qi0 >> 8, ph0 = (qi0 >> 4) & 15;
  const int nch = wid * 32 + l31;      // weight row this lane stages (A-operand)
  f32x16 acc = fzero16();
#pragma unroll
  for (int k0 = 0; k0 < 128; k0 += 16) {
    short8 af = *(const short8*)(ao + ((size_t)(qi0 + l31) * 32 + bs) * CC + k0 + 8 * g);
    short8 bf = *(const short8*)(wbf + nch * CC + k0 + 8 * g);
    acc = __builtin_amdgcn_mfma_f32_32x32x16_bf16(bf, af, acc, 0, 0, 0);
  }
  // lane holds token qi0+l31; channel rows ch = wid*32 + (r&3)+8*(r>>2)+4g
  const int h = bh * 16 + ph0 + (l31 >> 4);
  const int w = bw * 16 + (l31 & 15);
  const size_t sp = (size_t)h * 64 + w;
#pragma unroll
  for (int r = 0; r < 16; ++r) {
    const int ch = wid * 32 + (r & 3) + 8 * (r >> 2) + 4 * g;
    const size_t adr = (((size_t)(nb * CC + ch) * 4 + t) << 12) + sp;
    out[adr] = acc[r] + b_out[ch];
  }
}

extern "C" void kernel_launch(void* const* d_in, const int* in_sizes, int n_in,
                              void* d_out, int out_size, void* d_ws, size_t ws_size,
                              hipStream_t stream) {
  (void)in_sizes; (void)n_in; (void)out_size; (void)ws_size;
  const float* q   = (const float*)d_in[0];
  const float* k   = (const float*)d_in[1];
  const float* v   = (const float*)d_in[2];
  const float* pq  = (const float*)d_in[3];
  const float* pk  = (const float*)d_in[4];
  const float* wil = (const float*)d_in[5];
  const float* bil = (const float*)d_in[6];
  const float* wol = (const float*)d_in[7];
  const float* bol = (const float*)d_in[8];
  const float* wis = (const float*)d_in[9];
  const float* bis = (const float*)d_in[10];
  const float* wos = (const float*)d_in[11];
  const float* bos = (const float*)d_in[12];

  short* qs     = (short*)d_ws;            // 4.19M shorts each region
  short* ksb    = qs + 4194304;
  short* vsb    = ksb + 4194304;
  short* ao     = vsb + 4194304;
  short* pos_ct = ao + 4194304;
  short* wbf    = pos_ct + 4194304;        // 131072 shorts

  k_cvtw<<<dim3(64), dim3(256), 0, stream>>>(wil, wol, wis, wos, wbf);
  k_proj_long<<<dim3(1024), dim3(256), 0, stream>>>(q, k, v, pq, pk, wbf, bil,
                                                    qs, ksb, vsb, pos_ct);
  k_attn<64, 512, 1><<<dim3(1024), dim3(256), 0, stream>>>(qs, ksb, vsb, ao);
  k_mid<<<dim3(1024), dim3(256), 0, stream>>>(ao, pos_ct, wbf + 49152, bol,
                                              wbf + 65536, bis, qs, ksb, vsb);
  k_attn<1024, 32, 2><<<dim3(2048), dim3(256), 0, stream>>>(qs, ksb, vsb, ao);
  k_out_short<<<dim3(1024), dim3(256), 0, stream>>>(ao, wbf + 114688, bos,
                                                    (float*)d_out);
}

// Round 18
// 130.211 us; speedup vs baseline: 1.1196x; 1.0819x over previous
//
#include <hip/hip_runtime.h>
#include <hip/hip_bf16.h>

#define CC 128

typedef __attribute__((ext_vector_type(8))) short short8;
typedef __attribute__((ext_vector_type(16))) float f32x16;

union I4S8 { int4 i; short8 s; int2 h[2]; };

__device__ __forceinline__ unsigned short f2bfu(float f) {
  union { float f; unsigned int i; } x; x.f = f;
  unsigned int r = x.i + 0x7fffu + ((x.i >> 16) & 1u);
  return (unsigned short)(r >> 16);
}
__device__ __forceinline__ short f2bfs(float f) { return (short)f2bfu(f); }
// packed f32x2 -> bf16x2 via compiler intrinsic (RNE, emits v_cvt_pk_bf16_f32)
__device__ __forceinline__ unsigned int pk2(float a, float b) {
  union { __hip_bfloat162 h; unsigned int u; } c;
  c.h = __float22bfloat162_rn(make_float2(a, b));
  return c.u;
}
__device__ __forceinline__ float bflo(unsigned int u) {
  union { unsigned int i; float f; } x; x.i = u << 16; return x.f;
}
__device__ __forceinline__ float bfhi(unsigned int u) {
  union { unsigned int i; float f; } x; x.i = u & 0xffff0000u; return x.f;
}
// guaranteed single-instruction 2^x (v_exp_f32); 1-src/1-dst asm fallback
__device__ __forceinline__ float exp2_raw(float x) {
#if __has_builtin(__builtin_amdgcn_exp2f)
  return __builtin_amdgcn_exp2f(x);
#else
  float r; asm("v_exp_f32 %0, %1" : "=v"(r) : "v"(x)); return r;
#endif
}
__device__ __forceinline__ f32x16 fzero16() {
  f32x16 z;
#pragma unroll
  for (int i = 0; i < 16; ++i) z[i] = 0.f;
  return z;
}
__device__ __forceinline__ void ld8f(const float* p, float* f) {
  float4 a = *(const float4*)p, b = *(const float4*)(p + 4);
  f[0]=a.x; f[1]=a.y; f[2]=a.z; f[3]=a.w; f[4]=b.x; f[5]=b.y; f[6]=b.z; f[7]=b.w;
}

// 1/sqrt(16) * log2(e): folded into Q so attention works in log2 domain
#define QSC 0.3606737602f

// ---------------- W: fp32 -> bf16 weight conversion ----------------
__global__ __launch_bounds__(256) void k_cvtw(
    const float* __restrict__ wil, const float* __restrict__ wol,
    const float* __restrict__ wis, const float* __restrict__ wos,
    short* __restrict__ o) {
  const int idx = (blockIdx.x * 256 + threadIdx.x) * 8;
  const float* src; int off;
  if (idx < 49152)       { src = wil; off = idx; }
  else if (idx < 65536)  { src = wol; off = idx - 49152; }
  else if (idx < 114688) { src = wis; off = idx - 65536; }
  else                   { src = wos; off = idx - 114688; }
  float f[8];
  ld8f(src + off, f);
  short8 r;
#pragma unroll
  for (int j = 0; j < 8; ++j) r[j] = f2bfs(f[j]);
  *(short8*)(o + idx) = r;
}

// ---------------- K1: long QKV projection, MFMA ----------------
// Emits bf16 Q/K/V [pair=b*8+hh][l][d] and pos_ct[c][tok] bf16.
// Coalesced stager: thread = (channel, w-quad); 4 consecutive lanes read one
// contiguous 64B row -> 16 fully-used cache lines per instruction.
__global__ __launch_bounds__(256) void k_proj_long(
    const float* __restrict__ q, const float* __restrict__ k,
    const float* __restrict__ v, const float* __restrict__ pq,
    const float* __restrict__ pk,
    const short* __restrict__ wbf, const float* __restrict__ b_in,
    short* __restrict__ qb, short* __restrict__ kb, short* __restrict__ vb,
    short* __restrict__ pos_ct) {
  __shared__ short XQ[32][132], XK[32][132], XV[32][132];
  const int tid = threadIdx.x;
  const int wid = tid >> 6, lane = tid & 63;
  const int l31 = lane & 31, g = lane >> 5;
  const int tok0 = blockIdx.x * 32;
  const int l = tok0 >> 9, b0 = tok0 & 511;
  const int t = l >> 4, bh = (l >> 2) & 3, bw = l & 3;
  const int nb = b0 >> 8, ph0 = (b0 >> 4) & 15;
  {
    const int wq = tid & 3;           // w-quad: 4 floats
    const int cb = tid >> 2;          // 0..63
    const int h0 = bh * 16 + ph0;
    const int w0 = bw * 16 + wq * 4;
#pragma unroll
    for (int itc = 0; itc < 2; ++itc) {
      const int c = cb + 64 * itc;
      const size_t gb0 = (((size_t)(nb * CC + c) * 4 + t) << 12) + (size_t)h0 * 64 + w0;
#pragma unroll
      for (int half = 0; half < 2; ++half) {
        const size_t gb = gb0 + (size_t)half * 64;
        const float4 aq = *(const float4*)(q + gb);
        const float4 pv = *(const float4*)(pq + gb);
        const float4 ak = *(const float4*)(k + gb);
        const float4 pk4 = *(const float4*)(pk + gb);
        const float4 av = *(const float4*)(v + gb);
        uint2 ps; ps.x = pk2(pv.x, pv.y); ps.y = pk2(pv.z, pv.w);
        *(uint2*)(pos_ct + (size_t)c * 32768 + tok0 + half * 16 + wq * 4) = ps;
        const int tb = half * 16 + wq * 4;
        XQ[tb + 0][c] = f2bfs(aq.x + pv.x);
        XQ[tb + 1][c] = f2bfs(aq.y + pv.y);
        XQ[tb + 2][c] = f2bfs(aq.z + pv.z);
        XQ[tb + 3][c] = f2bfs(aq.w + pv.w);
        XK[tb + 0][c] = f2bfs(ak.x + pk4.x);
        XK[tb + 1][c] = f2bfs(ak.y + pk4.y);
        XK[tb + 2][c] = f2bfs(ak.z + pk4.z);
        XK[tb + 3][c] = f2bfs(ak.w + pk4.w);
        XV[tb + 0][c] = f2bfs(av.x);
        XV[tb + 1][c] = f2bfs(av.y);
        XV[tb + 2][c] = f2bfs(av.z);
        XV[tb + 3][c] = f2bfs(av.w);
      }
    }
  }
  __syncthreads();
  for (int i = 0; i < 3; ++i) {
    const int nt = wid + 4 * i;
    const int nch = nt * 32 + l31;
    const int which = nt >> 2;
    const short (*X)[132] = (which == 0) ? XQ : (which == 1) ? XK : XV;
    f32x16 acc = fzero16();
#pragma unroll
    for (int k0 = 0; k0 < 128; k0 += 16) {
      I4S8 af;
      af.h[0] = *(const int2*)&X[l31][k0 + 8 * g];
      af.h[1] = *(const int2*)&X[l31][k0 + 8 * g + 4];
      short8 bf = *(const short8*)(wbf + nch * CC + k0 + 8 * g);
      acc = __builtin_amdgcn_mfma_f32_32x32x16_bf16(af.s, bf, acc, 0, 0, 0);
    }
    const float bias = b_in[nch];
    const int hh = (nch >> 4) & 7, d = nch & 15;
    short* dst = (which == 0) ? qb : (which == 1) ? kb : vb;
    const float sc = (which == 0) ? QSC : 1.0f;
#pragma unroll
    for (int r = 0; r < 16; ++r) {
      const int tt = (r & 3) + 8 * (r >> 2) + 4 * g;
      dst[((size_t)((b0 + tt) * 8 + hh) * 64 + l) * 16 + d] =
          f2bfs((acc[r] + bias) * sc);
    }
  }
}

// ---------------- K2: unified MFMA flash attention ----------------
// Q64/wave, optional split-K (static-max exp2 makes partials additive).
// Single-buffer V^T LDS tile [17][36] (ones row 16 -> acc[8]=lsum),
// unroll-2 key loop, s_setprio around MFMA clusters.
template<int SEQ, int BATCH, int SPLITK>
__global__ __launch_bounds__(256) void k_attn(
    const short* __restrict__ qsp, const short* __restrict__ ksp,
    const short* __restrict__ vsp, short* __restrict__ ao) {
  __shared__ short vt[4][17 * 36];
  __shared__ float comb[2][64][19];   // used only when SPLITK==2
  const int tid = threadIdx.x;
  const int wid = tid >> 6, lane = tid & 63;
  const int l31 = lane & 31, g = lane >> 5;
  constexpr int QG = SEQ / 64;
  constexpr int NBLK = (BATCH * 8 * QG * SPLITK) / 4;
  // XCD-chunk swizzle (bijective: NBLK % 8 == 0)
  const int blk = (blockIdx.x & 7) * (NBLK / 8) + (blockIdx.x >> 3);
  const int gw = blk * 4 + wid;
  const int kh = (SPLITK == 2) ? (gw & 1) : 0;
  const int rest = (SPLITK == 2) ? (gw >> 1) : gw;
  const int pair = rest / QG;
  const int q0 = (rest % QG) * 64;
  const int batch = pair >> 3, hh = pair & 7;
  const size_t pbase = (size_t)pair * (SEQ * 16);
  short* vtw = &vt[wid][0];
  // ones row (A rows 16..31): 18 lanes write one b32 each, once
  if (lane < 18) *(int*)(vtw + 16 * 36 + 2 * lane) = 0x3F803F80;

  const short8 qf0 = *(const short8*)(qsp + pbase + (size_t)(q0 + l31) * 16 + 8 * g);
  const short8 qf1 = *(const short8*)(qsp + pbase + (size_t)(q0 + 32 + l31) * 16 + 8 * g);

  f32x16 acc0 = fzero16(), acc1 = fzero16();
  const int arow = (l31 < 16) ? l31 : 16;
  const short* vtr = vtw + arow * 36;
  const int kbeg = kh * (SEQ / SPLITK), kend = kbeg + SEQ / SPLITK;

#pragma unroll 2
  for (int k0 = kbeg; k0 < kend; k0 += 32) {
    const short8 kf = *(const short8*)(ksp + pbase + (size_t)(k0 + l31) * 16 + 8 * g);
    const short8 vf = *(const short8*)(vsp + pbase + (size_t)(k0 + l31) * 16 + 8 * g);
#pragma unroll
    for (int j = 0; j < 8; ++j)
      vtw[(8 * g + j) * 36 + l31] = vf[j];

    __builtin_amdgcn_s_setprio(1);
    f32x16 s0 = __builtin_amdgcn_mfma_f32_32x32x16_bf16(kf, qf0, fzero16(), 0, 0, 0);
    f32x16 s1 = __builtin_amdgcn_mfma_f32_32x32x16_bf16(kf, qf1, fzero16(), 0, 0, 0);
    __builtin_amdgcn_s_setprio(0);

    I4S8 pa0, pb0, pa1, pb1;
#pragma unroll
    for (int j = 0; j < 4; ++j) {
      pa0.i[j] = (int)pk2(exp2_raw(s0[2 * j]), exp2_raw(s0[2 * j + 1]));
      pb0.i[j] = (int)pk2(exp2_raw(s0[8 + 2 * j]), exp2_raw(s0[9 + 2 * j]));
    }
#pragma unroll
    for (int j = 0; j < 4; ++j) {
      pa1.i[j] = (int)pk2(exp2_raw(s1[2 * j]), exp2_raw(s1[2 * j + 1]));
      pb1.i[j] = (int)pk2(exp2_raw(s1[8 + 2 * j]), exp2_raw(s1[9 + 2 * j]));
    }

    I4S8 a1, a2;
    a1.h[0] = *(const int2*)(vtr + 4 * g);
    a1.h[1] = *(const int2*)(vtr + 8 + 4 * g);
    a2.h[0] = *(const int2*)(vtr + 16 + 4 * g);
    a2.h[1] = *(const int2*)(vtr + 24 + 4 * g);
    __builtin_amdgcn_s_setprio(1);
    acc0 = __builtin_amdgcn_mfma_f32_32x32x16_bf16(a1.s, pa0.s, acc0, 0, 0, 0);
    acc0 = __builtin_amdgcn_mfma_f32_32x32x16_bf16(a2.s, pb0.s, acc0, 0, 0, 0);
    acc1 = __builtin_amdgcn_mfma_f32_32x32x16_bf16(a1.s, pa1.s, acc1, 0, 0, 0);
    acc1 = __builtin_amdgcn_mfma_f32_32x32x16_bf16(a2.s, pb1.s, acc1, 0, 0, 0);
    __builtin_amdgcn_s_setprio(0);
  }

  if (SPLITK == 2) {
    // split-K combine: kh=1 deposits 18 partials/lane; kh=0 adds
    const int pi = wid >> 1;
    if (kh == 1) {
#pragma unroll
      for (int r = 0; r < 9; ++r) {
        comb[pi][lane][r] = acc0[r];
        comb[pi][lane][9 + r] = acc1[r];
      }
    }
    __syncthreads();
    if (kh == 1) return;
#pragma unroll
    for (int r = 0; r < 9; ++r) {
      acc0[r] += comb[pi][lane][r];
      acc1[r] += comb[pi][lane][9 + r];
    }
  }

  const float inv0 = 1.0f / acc0[8];   // ones-row accumulation = full lsum
  const float inv1 = 1.0f / acc1[8];
  const int qi = q0 + l31;
  short* dst0 = ao + ((size_t)qi * BATCH + batch) * CC + hh * 16 + 4 * g;
  short* dst1 = ao + ((size_t)(qi + 32) * BATCH + batch) * CC + hh * 16 + 4 * g;
  uint2 o1, o2;
  o1.x = pk2(acc0[0] * inv0, acc0[1] * inv0);
  o1.y = pk2(acc0[2] * inv0, acc0[3] * inv0);
  o2.x = pk2(acc0[4] * inv0, acc0[5] * inv0);
  o2.y = pk2(acc0[6] * inv0, acc0[7] * inv0);
  *(uint2*)dst0 = o1;
  *(uint2*)(dst0 + 8) = o2;
  o1.x = pk2(acc1[0] * inv1, acc1[1] * inv1);
  o1.y = pk2(acc1[2] * inv1, acc1[3] * inv1);
  o2.x = pk2(acc1[4] * inv1, acc1[5] * inv1);
  o2.y = pk2(acc1[6] * inv1, acc1[7] * inv1);
  *(uint2*)dst1 = o1;
  *(uint2*)(dst1 + 8) = o2;
}

// ---------------- K3: long out-proj + pos + short QKV proj (MFMA x2) ----------------
// ao tile (8KB contiguous) staged to LDS with fully-coalesced loads.
__global__ __launch_bounds__(256) void k_mid(
    const short* __restrict__ ao, const short* __restrict__ pos_ct,
    const short* __restrict__ wobf, const float* __restrict__ b_out_l,
    const short* __restrict__ wibf, const float* __restrict__ b_in_s,
    short* __restrict__ qb, short* __restrict__ kb, short* __restrict__ vb) {
  __shared__ short YQK[32][132], YV[32][132], AOL[32][132];
  const int tid = threadIdx.x;
  const int wid = tid >> 6, lane = tid & 63;
  const int l31 = lane & 31, g = lane >> 5;
  const int tok0 = blockIdx.x * 32;
  const int l = tok0 >> 9, b0 = tok0 & 511;
  const int t = l >> 4, bh = (l >> 2) & 3, bw = l & 3;
  const int nb = b0 >> 8, ph0 = (b0 >> 4) & 15;
  {
    const short8* src = (const short8*)(ao + (size_t)tok0 * CC);
#pragma unroll
    for (int it = 0; it < 2; ++it) {
      const int idx = it * 256 + tid;        // 16B chunk index, 0..511
      const int row = idx >> 4, col = (idx & 15) * 8;  // 16 chunks per 128-short row
      I4S8 vsrc; vsrc.s = src[idx];
      *(int2*)&AOL[row][col] = vsrc.h[0];
      *(int2*)&AOL[row][col + 4] = vsrc.h[1];
    }
  }
  __syncthreads();
  {
    const int nch = wid * 32 + l31;
    f32x16 acc = fzero16();
#pragma unroll
    for (int k0 = 0; k0 < 128; k0 += 16) {
      I4S8 af;
      af.h[0] = *(const int2*)&AOL[l31][k0 + 8 * g];
      af.h[1] = *(const int2*)&AOL[l31][k0 + 8 * g + 4];
      short8 bf = *(const short8*)(wobf + nch * CC + k0 + 8 * g);
      acc = __builtin_amdgcn_mfma_f32_32x32x16_bf16(af.s, bf, acc, 0, 0, 0);
    }
    const float bias = b_out_l[nch];
    float pos[16];
#pragma unroll
    for (int rr = 0; rr < 4; ++rr) {
      int2 pp = *(const int2*)(pos_ct + (size_t)nch * 32768 + tok0 + rr * 8 + 4 * g);
      pos[rr * 4 + 0] = bflo((unsigned int)pp.x);
      pos[rr * 4 + 1] = bfhi((unsigned int)pp.x);
      pos[rr * 4 + 2] = bflo((unsigned int)pp.y);
      pos[rr * 4 + 3] = bfhi((unsigned int)pp.y);
    }
#pragma unroll
    for (int r = 0; r < 16; ++r) {
      const int tt = (r & 3) + 8 * (r >> 2) + 4 * g;
      const float y = acc[r] + bias;
      YV[tt][nch] = f2bfs(y);
      YQK[tt][nch] = f2bfs(y + pos[r]);
    }
  }
  __syncthreads();
  const int bs = nb * 16 + bh * 4 + bw;
  const int ls0 = (t * 16 + ph0) * 16;
  for (int i = 0; i < 3; ++i) {
    const int nt = wid + 4 * i;
    const int nch = nt * 32 + l31;
    const int which = nt >> 2;
    const short (*X)[132] = (which == 2) ? YV : YQK;
    f32x16 acc = fzero16();
#pragma unroll
    for (int k0 = 0; k0 < 128; k0 += 16) {
      I4S8 af;
      af.h[0] = *(const int2*)&X[l31][k0 + 8 * g];
      af.h[1] = *(const int2*)&X[l31][k0 + 8 * g + 4];
      short8 bf = *(const short8*)(wibf + nch * CC + k0 + 8 * g);
      acc = __builtin_amdgcn_mfma_f32_32x32x16_bf16(af.s, bf, acc, 0, 0, 0);
    }
    const float bias = b_in_s[nch];
    const int hh = (nch >> 4) & 7, d = nch & 15;
    short* dst = (which == 0) ? qb : (which == 1) ? kb : vb;
    const float sc = (which == 0) ? QSC : 1.0f;
    const size_t base = ((size_t)(bs * 8 + hh) * 1024 + ls0) * 16 + d;
#pragma unroll
    for (int r = 0; r < 16; ++r) {
      const int tt = (r & 3) + 8 * (r >> 2) + 4 * g;
      dst[base + (size_t)tt * 16] = f2bfs((acc[r] + bias) * sc);
    }
  }
}

// ---------------- K4: short out-proj + scatter, MFMA (swapped operands) ----------------
// ao rows staged to LDS with row-coalesced loads (4 full 256B rows/instr);
// C^T = mfma(W, AO): lane = token, regs = channels -> contiguous stores.
__global__ __launch_bounds__(256) void k_out_short(
    const short* __restrict__ ao, const short* __restrict__ wbf,
    const float* __restrict__ b_out, float* __restrict__ out) {
  __shared__ short AOL[32][132];
  const int tid = threadIdx.x;
  const int wid = tid >> 6, lane = tid & 63;
  const int l31 = lane & 31, g = lane >> 5;
  const int bs = blockIdx.x & 31;
  const int qi0 = (blockIdx.x >> 5) << 5;
  const int nb = bs >> 4, bh = (bs >> 2) & 3, bw = bs & 3;
  const int t = qi0 >> 8, ph0 = (qi0 >> 4) & 15;
  {
#pragma unroll
    for (int it = 0; it < 2; ++it) {
      const int idx = it * 256 + tid;        // 16B chunk, 0..511
      const int row = idx >> 4, seg = idx & 15;
      I4S8 vsrc;
      vsrc.s = *(const short8*)(ao + ((size_t)(qi0 + row) * 32 + bs) * CC + seg * 8);
      *(int2*)&AOL[row][seg * 8] = vsrc.h[0];
      *(int2*)&AOL[row][seg * 8 + 4] = vsrc.h[1];
    }
  }
  __syncthreads();
  const int nch = wid * 32 + l31;      // weight row this lane stages (A-operand)
  f32x16 acc = fzero16();
#pragma unroll
  for (int k0 = 0; k0 < 128; k0 += 16) {
    I4S8 af;
    af.h[0] = *(const int2*)&AOL[l31][k0 + 8 * g];
    af.h[1] = *(const int2*)&AOL[l31][k0 + 8 * g + 4];
    short8 bf = *(const short8*)(wbf + nch * CC + k0 + 8 * g);
    acc = __builtin_amdgcn_mfma_f32_32x32x16_bf16(bf, af.s, acc, 0, 0, 0);
  }
  // lane holds token qi0+l31; channel rows ch = wid*32 + (r&3)+8*(r>>2)+4g
  const int h = bh * 16 + ph0 + (l31 >> 4);
  const int w = bw * 16 + (l31 & 15);
  const size_t sp = (size_t)h * 64 + w;
#pragma unroll
  for (int r = 0; r < 16; ++r) {
    const int ch = wid * 32 + (r & 3) + 8 * (r >> 2) + 4 * g;
    const size_t adr = (((size_t)(nb * CC + ch) * 4 + t) << 12) + sp;
    out[adr] = acc[r] + b_out[ch];
  }
}

extern "C" void kernel_launch(void* const* d_in, const int* in_sizes, int n_in,
                              void* d_out, int out_size, void* d_ws, size_t ws_size,
                              hipStream_t stream) {
  (void)in_sizes; (void)n_in; (void)out_size; (void)ws_size;
  const float* q   = (const float*)d_in[0];
  const float* k   = (const float*)d_in[1];
  const float* v   = (const float*)d_in[2];
  const float* pq  = (const float*)d_in[3];
  const float* pk  = (const float*)d_in[4];
  const float* wil = (const float*)d_in[5];
  const float* bil = (const float*)d_in[6];
  const float* wol = (const float*)d_in[7];
  const float* bol = (const float*)d_in[8];
  const float* wis = (const float*)d_in[9];
  const float* bis = (const float*)d_in[10];
  const float* wos = (const float*)d_in[11];
  const float* bos = (const float*)d_in[12];

  short* qs     = (short*)d_ws;            // 4.19M shorts each region
  short* ksb    = qs + 4194304;
  short* vsb    = ksb + 4194304;
  short* ao     = vsb + 4194304;
  short* pos_ct = ao + 4194304;
  short* wbf    = pos_ct + 4194304;        // 131072 shorts

  k_cvtw<<<dim3(64), dim3(256), 0, stream>>>(wil, wol, wis, wos, wbf);
  k_proj_long<<<dim3(1024), dim3(256), 0, stream>>>(q, k, v, pq, pk, wbf, bil,
                                                    qs, ksb, vsb, pos_ct);
  k_attn<64, 512, 1><<<dim3(1024), dim3(256), 0, stream>>>(qs, ksb, vsb, ao);
  k_mid<<<dim3(1024), dim3(256), 0, stream>>>(ao, pos_ct, wbf + 49152, bol,
                                              wbf + 65536, bis, qs, ksb, vsb);
  k_attn<1024, 32, 2><<<dim3(2048), dim3(256), 0, stream>>>(qs, ksb, vsb, ao);
  k_out_short<<<dim3(1024), dim3(256), 0, stream>>>(ao, wbf + 114688, bos,
                                                    (float*)d_out);
}